// Round 1
// baseline (597.282 us; speedup 1.0000x reference)
//
#include <hip/hip_runtime.h>

// Problem constants (fixed by setup_inputs)
#define B_    8
#define CIN   3
#define H_    512
#define W_    512
#define COUT  64
#define E_    3

typedef float v4f __attribute__((ext_vector_type(4)));

// One block: batch b (= blockIdx.x % 8, XCD-affinity), 2 output rows, full width,
// all 64 output channels. 256 threads: tid>>7 = row (0..1), tid&127 = w-segment
// of 4 pixels. Each thread keeps the 3(ci)x3(kh)x6(w) input window in VGPRs and
// loops channels; weights are block-uniform -> scalar loads; output stored NT.
__global__ __launch_bounds__(256)
void conv_fused(const float* __restrict__ x,
                const float* __restrict__ vin,    // extra_inputs [B, COUT*E]
                const float* __restrict__ wm,     // w_main [COUT, CIN, 3, 3]
                const float* __restrict__ bm,     // b_main [COUT]
                const float* __restrict__ we,     // w_extra [COUT, E, 3, 3]
                const float* __restrict__ be,     // b_extra [COUT]
                float* __restrict__ out)          // [B, COUT, H, W]
{
    // Per-(b,c) summaries of the constant "extra" conv contribution:
    // Cfull = b_main + b_extra + sum of all 9 wc taps (interior value)
    // R0/R2 = top/bottom row tap-sums, C0/C2 = left/right col tap-sums,
    // K** = corner taps (add back double-subtracted corners).
    __shared__ float sCfull[COUT], sR0[COUT], sR2[COUT], sC0[COUT], sC2[COUT],
                     sK00[COUT], sK02[COUT], sK20[COUT], sK22[COUT];

    const int b   = blockIdx.x & 7;    // 8 batches <-> 8 XCDs (L2 locality heuristic)
    const int til = blockIdx.x >> 3;   // 0..255 row tiles
    const int tid = threadIdx.x;

    if (tid < COUT) {
        const int c = tid;
        const float* wep = we + c * (E_ * 9);
        const float v0 = vin[b * (COUT * E_) + c * E_ + 0];
        const float v1 = vin[b * (COUT * E_) + c * E_ + 1];
        const float v2 = vin[b * (COUT * E_) + c * E_ + 2];
        float wc[9];
        #pragma unroll
        for (int t = 0; t < 9; ++t)
            wc[t] = v0 * wep[t] + v1 * wep[9 + t] + v2 * wep[18 + t];
        float s9 = 0.f;
        #pragma unroll
        for (int t = 0; t < 9; ++t) s9 += wc[t];
        sCfull[c] = bm[c] + be[c] + s9;
        sR0[c] = wc[0] + wc[1] + wc[2];
        sR2[c] = wc[6] + wc[7] + wc[8];
        sC0[c] = wc[0] + wc[3] + wc[6];
        sC2[c] = wc[2] + wc[5] + wc[8];
        sK00[c] = wc[0]; sK02[c] = wc[2]; sK20[c] = wc[6]; sK22[c] = wc[8];
    }
    __syncthreads();

    const int row  = tid >> 7;       // 0..1
    const int wseg = tid & 127;      // 0..127
    const int w0   = wseg << 2;      // 0,4,...,508
    const int h    = til * 2 + row;  // 0..511

    // Load the input neighborhood once: xr[ci][kh][t] = x[b,ci,h+kh-1,w0-1+t],
    // zero for out-of-range (matches zero padding). float4 segment is 16B-aligned.
    float xr[CIN][3][6];
    #pragma unroll
    for (int ci = 0; ci < CIN; ++ci) {
        #pragma unroll
        for (int kh = 0; kh < 3; ++kh) {
            const int y = h + kh - 1;
            if ((unsigned)y < (unsigned)H_) {
                const float* rp = x + ((size_t)(b * CIN + ci) * H_ + y) * W_;
                const v4f m = *(const v4f*)(rp + w0);
                xr[ci][kh][1] = m.x; xr[ci][kh][2] = m.y;
                xr[ci][kh][3] = m.z; xr[ci][kh][4] = m.w;
                xr[ci][kh][0] = (w0 > 0)   ? rp[w0 - 1] : 0.f;
                xr[ci][kh][5] = (w0 < 508) ? rp[w0 + 4] : 0.f;
            } else {
                #pragma unroll
                for (int t = 0; t < 6; ++t) xr[ci][kh][t] = 0.f;
            }
        }
    }

    const bool htop = (h == 0), hbot = (h == H_ - 1);
    const bool wlft = (w0 == 0), wrgt = (w0 == 508);
    float* outp = out + ((size_t)(b * COUT) * H_ + h) * W_ + w0;

    #pragma unroll 2
    for (int c = 0; c < COUT; ++c) {
        const int cu = __builtin_amdgcn_readfirstlane(c);   // assert uniformity -> s_load weights
        const float* wp = wm + cu * 27;

        float base = sCfull[cu];
        if (htop) base -= sR0[cu];
        if (hbot) base -= sR2[cu];
        float a0 = base, a1 = base, a2 = base, a3 = base;
        if (wlft) {  // pixel w==0 lives at a0
            a0 -= sC0[cu];
            if (htop) a0 += sK00[cu];
            if (hbot) a0 += sK20[cu];
        }
        if (wrgt) {  // pixel w==511 lives at a3
            a3 -= sC2[cu];
            if (htop) a3 += sK02[cu];
            if (hbot) a3 += sK22[cu];
        }

        #pragma unroll
        for (int ci = 0; ci < CIN; ++ci) {
            #pragma unroll
            for (int kh = 0; kh < 3; ++kh) {
                #pragma unroll
                for (int kw = 0; kw < 3; ++kw) {
                    const float wv = wp[ci * 9 + kh * 3 + kw];
                    a0 += xr[ci][kh][kw + 0] * wv;
                    a1 += xr[ci][kh][kw + 1] * wv;
                    a2 += xr[ci][kh][kw + 2] * wv;
                    a3 += xr[ci][kh][kw + 3] * wv;
                }
            }
        }

        v4f o; o.x = a0; o.y = a1; o.z = a2; o.w = a3;
        // NT store: 537 MB write stream should not evict x from L2.
        __builtin_nontemporal_store(o, (v4f*)(outp + (size_t)cu * (H_ * W_)));
    }
}

extern "C" void kernel_launch(void* const* d_in, const int* in_sizes, int n_in,
                              void* d_out, int out_size, void* d_ws, size_t ws_size,
                              hipStream_t stream) {
    const float* x   = (const float*)d_in[0];
    const float* vin = (const float*)d_in[1];
    const float* wmn = (const float*)d_in[2];
    const float* bmn = (const float*)d_in[3];
    const float* wex = (const float*)d_in[4];
    const float* bex = (const float*)d_in[5];
    float* out = (float*)d_out;

    const int blocks = B_ * (H_ / 2);  // 2048
    conv_fused<<<blocks, 256, 0, stream>>>(x, vin, wmn, bmn, wex, bex, out);
}